// Round 2
// baseline (2165.196 us; speedup 1.0000x reference)
//
#include <hip/hip_runtime.h>

typedef _Float16 half_t;
typedef __attribute__((ext_vector_type(2))) _Float16 half2_t;

__device__ __forceinline__ half2_t bc2(unsigned int u){ return __builtin_bit_cast(half2_t, u); }
__device__ __forceinline__ float fdot2f(half2_t a, half2_t b, float c){
  return __builtin_amdgcn_fdot2(a, b, c, false);
}
__device__ __forceinline__ float rcp_f(float x){ return __builtin_amdgcn_rcpf(x); }
__device__ __forceinline__ float sigmoidf_(float x){ return rcp_f(1.0f+__expf(-x)); }
__device__ __forceinline__ float tanhf_(float x){ return 1.0f - 2.0f*rcp_f(__expf(2.0f*x)+1.0f); }

// Barrier WITHOUT vmcnt drain: LDS ordering only. Keeps prefetch loads in flight.
__device__ __forceinline__ void bar(){
  asm volatile("s_waitcnt lgkmcnt(0)\n\ts_barrier" ::: "memory");
}

__device__ __forceinline__ void load16(const half_t* wp, int stride, uint4 (&buf)[16]){
  #pragma unroll
  for (int kc=0;kc<16;++kc)
    buf[kc] = *reinterpret_cast<const uint4*>(wp + (size_t)kc*stride);
}
__device__ __forceinline__ float dot16(const uint4 (&w)[16], const half_t* xp, float bias){
  float a0=bias,a1=0.f,a2=0.f,a3=0.f;
  #pragma unroll
  for (int kc=0;kc<16;++kc){
    uint4 x = *reinterpret_cast<const uint4*>(xp + kc*8);
    a0=fdot2f(bc2(w[kc].x),bc2(x.x),a0);
    a1=fdot2f(bc2(w[kc].y),bc2(x.y),a1);
    a2=fdot2f(bc2(w[kc].z),bc2(x.z),a2);
    a3=fdot2f(bc2(w[kc].w),bc2(x.w),a3);
  }
  return (a0+a1)+(a2+a3);
}

// Pack f32 matrix (R x K slice at coloff, row stride ld) -> f16 [K/8][RT][8] at row_off.
__global__ void pack_k(const float* __restrict__ src, half_t* __restrict__ dst,
                       int R, int K, int ld, int coloff, int RT, int row_off){
  int idx = blockIdx.x*blockDim.x + threadIdx.x;
  if (idx >= R*K) return;
  int r = idx / K, k = idx - r*K;
  int kc = k >> 3, j = k & 7;
  dst[((size_t)kc*RT + row_off + r)*8 + j] = (half_t)src[(size_t)r*ld + coloff + k];
}

__launch_bounds__(512, 1)
__global__ void gru_main(
    const float* __restrict__ received,
    const float* __restrict__ Wih0d0, const float* __restrict__ Wih0d1,
    const float* __restrict__ bx0d0, const float* __restrict__ bh0d0,
    const float* __restrict__ bx1d0, const float* __restrict__ bh1d0,
    const float* __restrict__ bx0d1, const float* __restrict__ bh0d1,
    const float* __restrict__ bx1d1, const float* __restrict__ bh1d1,
    const float* __restrict__ vW, const float* __restrict__ fc2b,
    const half_t* __restrict__ W0pack, const half_t* __restrict__ W1pack,
    const half_t* __restrict__ WsPack, const half_t* __restrict__ WhPack,
    const half_t* __restrict__ fc2Pack,
    half_t* __restrict__ o1h, half_t* __restrict__ o2h)
{
  const int dec = blockIdx.x >> 5;
  const int b   = blockIdx.x & 31;
  const int tid = threadIdx.x;

  const float* bx0  = dec ? bx0d1 : bx0d0;
  const float* bh0  = dec ? bh0d1 : bh0d0;
  const float* bx1  = dec ? bx1d1 : bx1d0;
  const float* bh1  = dec ? bh1d1 : bh1d0;
  const float* Wih0 = dec ? Wih0d1 : Wih0d0;
  const half_t* W0  = W0pack + (size_t)dec*49152;   // [16][384][8]  Whh0
  const half_t* W1  = W1pack + (size_t)dec*98304;   // [16][768][8]  rows 0-383 Wih1, 384-767 Whh1
  half_t* od = dec ? o2h : o1h;

  __shared__ __align__(16) half_t sh_hist[2][128][128];    // raw h history, col-swizzled by (t>>5)&1
  __shared__ __align__(16) half_t sh_histWh[2][128][128];  // hist @ Wh.T, row-swizzled by i&31
  __shared__ __align__(16) float  sh_hatt[2][128];
  __shared__ __align__(16) half_t sh_hatt_pk[2][128];
  __shared__ __align__(16) float  sh_hraw[2][128];
  __shared__ __align__(16) half_t sh_hraw_pk[2][128];
  __shared__ __align__(16) float  sh_gx[384];
  __shared__ __align__(16) float  sh_gh[384];
  __shared__ __align__(16) float  sh_g1x[384];
  __shared__ __align__(16) float  sh_g1h[384];
  __shared__ __align__(16) float  sh_sWs[2][128];
  __shared__ __align__(16) float  sh_logits[2][128];
  __shared__ __align__(16) float  sh_probs[2][128];
  __shared__ __align__(16) half_t sh_fc2in[2][256];        // [c | h_raw]
  __shared__ __align__(16) float  sh_x[2][4];              // double-buffered x
  __shared__ __align__(16) float  sh_vW[128];

  // ---- per-thread job setup (addresses / biases, loop-invariant) ----
  // JobA (P1, all): rows 0-383 = Whh0; rows 384-511 = Whh1 rows 0-127
  const half_t* ptrA; int strA; float bA;
  if (tid < 384){ ptrA = W0 + (size_t)tid*8;        strA = 3072; bA = bh0[tid]; }
  else          { ptrA = W1 + (size_t)(tid)*8 + 384*8; strA = 6144; bA = bh1[tid-384]; }
  // JobB (P1, tid<256): Whh1 rows 128-383
  const half_t* ptrB = W1 + (size_t)(512+tid)*8;    float bB = (tid<256)? bh1[128+tid] : 0.f;
  // JobC (P3, tid<384): Wih1 rows 0-383
  const half_t* ptrC = W1 + (size_t)tid*8;          float bC = (tid<384)? bx1[tid] : 0.f;
  // JobD (P5, all): mat = tid>>8 (0=Ws,1=Wh), l=(tid>>7)&1, row=tid&127
  const int dmat = tid>>8, dl = (tid>>7)&1, drow = tid&127;
  const half_t* ptrD = (dmat? WhPack : WsPack) + (size_t)drow*8;
  // JobE (P9, all): eh=k-half, el=layer, erow
  const int eh = tid&1, el = (tid>>8)&1, erow = (tid>>1)&127;
  const half_t* ptrE = fc2Pack + (size_t)eh*16384 + (size_t)erow*8;
  const float bE = eh ? 0.f : fc2b[erow];
  // gx0 weights (3 cols) held in regs
  float wx0=0.f,wx1=0.f,wx2=0.f,bgx=0.f;
  if (tid < 384){ wx0=Wih0[tid*3]; wx1=Wih0[tid*3+1]; wx2=Wih0[tid*3+2]; bgx=bx0[tid]; }

  const half_t* xA = (tid<384)? &sh_hatt_pk[0][0] : &sh_hatt_pk[1][0];
  const half_t* xB = &sh_hatt_pk[1][0];
  const half_t* xC = &sh_hraw_pk[0][0];
  const half_t* xD = &sh_hraw_pk[dl][0];
  const half_t* xE = &sh_fc2in[el][eh*128];

  uint4 bufP[16], bufQ[16];

  if (tid < 256){ int l=tid>>7, r=tid&127; sh_hatt[l][r]=0.f; sh_hatt_pk[l][r]=(half_t)0.f; }
  if (tid < 128) sh_vW[tid] = vW[tid];
  if (tid < 3)   sh_x[0][tid] = received[(b*128)*3 + tid];
  // prefetch step-0 JobA/JobB
  load16(ptrA, strA, bufP);
  if (tid < 256) load16(ptrB, 6144, bufQ);
  bar();

  for (int i=0; i<128; ++i){
    // ---- P1: gh0 (rows 0-383) + gh1 (rows 0-383 via A-tail and B) + gx0 ----
    {
      float g = dot16(bufP, xA, bA);
      if (tid < 384){
        sh_gh[tid] = g;
        float xv0=sh_x[i&1][0], xv1=sh_x[i&1][1], xv2=sh_x[i&1][2];
        sh_gx[tid] = bgx + wx0*xv0 + wx1*xv1 + wx2*xv2;
      } else {
        sh_g1h[tid-384] = g;
      }
      if (tid < 256){
        float g2 = dot16(bufQ, xB, bB);
        sh_g1h[128+tid] = g2;
      }
      if (tid < 384) load16(ptrC, 6144, bufQ);   // prefetch P3
    }
    bar();
    // ---- P2: layer0 cell ----
    if (tid < 128){
      float rr = sigmoidf_(sh_gx[tid]+sh_gh[tid]);
      float zz = sigmoidf_(sh_gx[128+tid]+sh_gh[128+tid]);
      float nn = tanhf_(sh_gx[256+tid] + rr*sh_gh[256+tid]);
      float h0 = (1.f-zz)*nn + zz*sh_hatt[0][tid];
      sh_hraw[0][tid]=h0;
      half_t hh=(half_t)h0;
      int pp = (((tid>>1) ^ (((i>>5)&1)<<4))<<1) | (tid&1);
      sh_hist[0][i][pp]=hh;
      sh_hraw_pk[0][tid]=hh; sh_fc2in[0][128+tid]=hh;
    }
    load16(ptrD, 1024, bufP);                    // prefetch P5
    bar();
    // ---- P3: g1x = Wih1 @ h0_raw ----
    if (tid < 384){
      sh_g1x[tid] = dot16(bufQ, xC, bC);
    }
    bar();
    // ---- P4: layer1 cell ----
    if (tid < 128){
      float rr = sigmoidf_(sh_g1x[tid]+sh_g1h[tid]);
      float zz = sigmoidf_(sh_g1x[128+tid]+sh_g1h[128+tid]);
      float nn = tanhf_(sh_g1x[256+tid] + rr*sh_g1h[256+tid]);
      float h1 = (1.f-zz)*nn + zz*sh_hatt[1][tid];
      sh_hraw[1][tid]=h1;
      half_t hh=(half_t)h1;
      int pp = (((tid>>1) ^ (((i>>5)&1)<<4))<<1) | (tid&1);
      sh_hist[1][i][pp]=hh;
      sh_hraw_pk[1][tid]=hh; sh_fc2in[1][128+tid]=hh;
      od[(size_t)(b*128+i)*128 + tid] = hh;
    }
    bar();
    // ---- P5: sWs / histWh projections ----
    {
      float dacc = dot16(bufP, xD, 0.f);
      if (dmat==0) sh_sWs[dl][drow] = dacc;
      else {
        int phys = (((drow>>1) ^ (i&31))<<1) | (drow&1);
        sh_histWh[dl][i][phys] = (half_t)dacc;
      }
      if (tid<3 && i<127) sh_x[(i+1)&1][tid] = received[(b*128+i+1)*3+tid];
      load16(ptrE, 1024, bufQ);                  // prefetch P9
    }
    bar();
    if (i > 0){
      // ---- P6: logits (2 lanes per (l,t)); prefetch next-step JobA ----
      load16(ptrA, strA, bufP);
      {
        int q=tid&1, t=(tid>>1)&127, l=tid>>8;
        float s=0.f;
        if (t<=i){
          const half_t* hrow = &sh_histWh[l][t][0];
          int tx = t&31;
          #pragma unroll 4
          for (int ji=0; ji<32; ++ji){
            int j = q*32+ji;
            half2_t h2 = *reinterpret_cast<const half2_t*>(hrow + ((j^tx)<<1));
            float2 sv = *reinterpret_cast<const float2*>(&sh_sWs[l][j*2]);
            float2 vv = *reinterpret_cast<const float2*>(&sh_vW[j*2]);
            s += tanhf_(sv.x + (float)h2[0])*vv.x;
            s += tanhf_(sv.y + (float)h2[1])*vv.y;
          }
        }
        s += __shfl_xor(s,1);
        if (q==0 && t<=i) sh_logits[l][t]=s;
      }
      bar();
      // ---- P7: masked softmax ----
      if (tid < 128){
        int l=tid>>6, lane=tid&63;
        float l0 = (lane<=i)    ? sh_logits[l][lane]    : -3e38f;
        float l1 = (lane+64<=i) ? sh_logits[l][lane+64] : -3e38f;
        float m = fmaxf(l0,l1);
        #pragma unroll
        for (int k=1;k<64;k<<=1) m = fmaxf(m, __shfl_xor(m,k));
        float p0 = (lane<=i)    ? __expf(l0-m) : 0.f;
        float p1 = (lane+64<=i) ? __expf(l1-m) : 0.f;
        float ss = p0+p1;
        #pragma unroll
        for (int k=1;k<64;k<<=1) ss += __shfl_xor(ss,k);
        float inv = rcp_f(ss);
        sh_probs[l][lane]=p0*inv; sh_probs[l][lane+64]=p1*inv;
      }
      bar();
      // ---- P8: context ----
      {
        int q=tid&3, o2=(tid>>2)&63, l=tid>>8;
        int swz = (q&1)<<4;
        float c0=0.f,c1=0.f;
        int t0=q*32;
        int tend = (t0+32 < i+1) ? t0+32 : i+1;
        for (int t=t0; t<tend; ++t){
          float a = sh_probs[l][t];
          half2_t h2 = *reinterpret_cast<const half2_t*>(&sh_hist[l][t][(o2^swz)<<1]);
          c0 += a*(float)h2[0]; c1 += a*(float)h2[1];
        }
        c0 += __shfl_xor(c0,1); c1 += __shfl_xor(c1,1);
        c0 += __shfl_xor(c0,2); c1 += __shfl_xor(c1,2);
        if (q==0){
          sh_fc2in[l][o2*2]   = (half_t)c0;
          sh_fc2in[l][o2*2+1] = (half_t)c1;
        }
      }
      bar();
      // ---- P9: h_att = fc2 @ [c|h_raw] (k-split 2-way, shfl combine) ----
      {
        float e = dot16(bufQ, xE, bE);
        e += __shfl_xor(e, 1);
        if (!(tid&1)){ sh_hatt[el][erow]=e; sh_hatt_pk[el][erow]=(half_t)e; }
        if (tid < 256) load16(ptrB, 6144, bufQ); // prefetch next-step JobB
      }
    } else {
      load16(ptrA, strA, bufP);                  // prefetch next-step JobA
      if (tid < 256){
        int l=tid>>7, row=tid&127;
        float hv = sh_hraw[l][row];
        sh_hatt[l][row]=hv; sh_hatt_pk[l][row]=(half_t)hv;
      }
      if (tid < 256) load16(ptrB, 6144, bufQ);   // prefetch next-step JobB
    }
    bar();
  }
}

// Final: out[b,t] = sigmoid(tanh(out_W . [o1[b,t] | o2[b,min(t+10,127)]] + out_b))
__global__ void out_kernel(const half_t* __restrict__ o1h, const half_t* __restrict__ o2h,
                           const float* __restrict__ outW, const float* __restrict__ outb,
                           float* __restrict__ dout){
  int tid = blockIdx.x*blockDim.x + threadIdx.x;
  int q = tid&3, job = tid>>2;
  int b = job>>7, t = job&127;
  int t2 = t+10; if (t2>127) t2=127;
  const half_t* r1 = o1h + (size_t)(b*128+t)*128;
  const half_t* r2 = o2h + (size_t)(b*128+t2)*128;
  float acc=0.f;
  for (int j=q*32; j<q*32+32; ++j) acc += outW[j]*(float)r1[j];
  for (int j=q*32; j<q*32+32; ++j) acc += outW[128+j]*(float)r2[j];
  acc += __shfl_xor(acc,1);
  acc += __shfl_xor(acc,2);
  if (q==0){
    float d = tanhf_(acc + outb[0]);
    dout[job] = rcp_f(1.f+__expf(-d));
  }
}

static inline void launch_pack(const void* src, half_t* dst, int R, int K, int ld,
                               int coloff, int RT, int row_off, hipStream_t s){
  int total = R*K;
  pack_k<<<(total+255)/256, 256, 0, s>>>((const float*)src, dst, R, K, ld, coloff, RT, row_off);
}

extern "C" void kernel_launch(void* const* d_in, const int* in_sizes, int n_in,
                              void* d_out, int out_size, void* d_ws, size_t ws_size,
                              hipStream_t stream) {
  const float* received = (const float*)d_in[0];
  const float* Wih1_0 = (const float*)d_in[1];
  const float* Whh1_0 = (const float*)d_in[2];
  const float* bih1_0 = (const float*)d_in[3];
  const float* bhh1_0 = (const float*)d_in[4];
  const float* Wih1_1 = (const float*)d_in[5];
  const float* Whh1_1 = (const float*)d_in[6];
  const float* bih1_1 = (const float*)d_in[7];
  const float* bhh1_1 = (const float*)d_in[8];
  const float* Wih2_0 = (const float*)d_in[9];
  const float* Whh2_0 = (const float*)d_in[10];
  const float* bih2_0 = (const float*)d_in[11];
  const float* bhh2_0 = (const float*)d_in[12];
  const float* Wih2_1 = (const float*)d_in[13];
  const float* Whh2_1 = (const float*)d_in[14];
  const float* bih2_1 = (const float*)d_in[15];
  const float* bhh2_1 = (const float*)d_in[16];
  const float* attn_W = (const float*)d_in[17];
  const float* v_W    = (const float*)d_in[18];
  const float* fc2_W  = (const float*)d_in[19];
  const float* fc2_b  = (const float*)d_in[20];
  const float* out_W  = (const float*)d_in[21];
  const float* out_b  = (const float*)d_in[22];

  half_t* ws = (half_t*)d_ws;
  half_t* W0pack  = ws + 0;        // 2 x [16][384][8] = 98304
  half_t* W1pack  = ws + 98304;    // 2 x [16][768][8] = 196608
  half_t* WsPack  = ws + 294912;   // [16][128][8] = 16384
  half_t* WhPack  = ws + 311296;   // 16384
  half_t* fc2Pack = ws + 327552;   // [32][128][8] = 32768
  half_t* o1h     = ws + 360448;   // 32*128*128 = 524288
  half_t* o2h     = ws + 884736;   // 524288

  launch_pack(Whh1_0, W0pack,          384, 128, 128, 0, 384, 0, stream);
  launch_pack(Whh2_0, W0pack + 49152,  384, 128, 128, 0, 384, 0, stream);
  launch_pack(Wih1_1, W1pack,          384, 128, 128, 0, 768, 0, stream);
  launch_pack(Whh1_1, W1pack,          384, 128, 128, 0, 768, 384, stream);
  launch_pack(Wih2_1, W1pack + 98304,  384, 128, 128, 0, 768, 0, stream);
  launch_pack(Whh2_1, W1pack + 98304,  384, 128, 128, 0, 768, 384, stream);
  launch_pack(attn_W, WsPack,          128, 128, 256, 0,   128, 0, stream);
  launch_pack(attn_W, WhPack,          128, 128, 256, 128, 128, 0, stream);
  launch_pack(fc2_W,  fc2Pack,         128, 256, 256, 0,   128, 0, stream);

  gru_main<<<64, 512, 0, stream>>>(
      received,
      Wih1_0, Wih2_0,
      bih1_0, bhh1_0, bih1_1, bhh1_1,
      bih2_0, bhh2_0, bih2_1, bhh2_1,
      v_W, fc2_b,
      W0pack, W1pack, WsPack, WhPack, fc2Pack,
      o1h, o2h);

  out_kernel<<<64, 256, 0, stream>>>(o1h, o2h, out_W, out_b, (float*)d_out);
}

// Round 3
// 2152.715 us; speedup vs baseline: 1.0058x; 1.0058x over previous
//
#include <hip/hip_runtime.h>

typedef _Float16 half_t;
typedef __attribute__((ext_vector_type(2))) _Float16 half2_t;

__device__ __forceinline__ half2_t bc2(unsigned int u){ return __builtin_bit_cast(half2_t, u); }
__device__ __forceinline__ float fdot2f(half2_t a, half2_t b, float c){
  return __builtin_amdgcn_fdot2(a, b, c, false);
}
__device__ __forceinline__ float rcp_f(float x){ return __builtin_amdgcn_rcpf(x); }
__device__ __forceinline__ float sigmoidf_(float x){ return rcp_f(1.0f+__expf(-x)); }
__device__ __forceinline__ float tanhf_(float x){ return 1.0f - 2.0f*rcp_f(__expf(2.0f*x)+1.0f); }

// Barrier WITHOUT vmcnt drain: LDS ordering only. Keeps prefetch loads in flight.
__device__ __forceinline__ void bar(){
  asm volatile("s_waitcnt lgkmcnt(0)\n\ts_barrier" ::: "memory");
}

__device__ __forceinline__ void load16(const half_t* wp, int stride, uint4 (&buf)[16]){
  #pragma unroll
  for (int kc=0;kc<16;++kc)
    buf[kc] = *reinterpret_cast<const uint4*>(wp + (size_t)kc*stride);
}
__device__ __forceinline__ float dot16(const uint4 (&w)[16], const half_t* xp, float bias){
  float a0=bias,a1=0.f,a2=0.f,a3=0.f;
  #pragma unroll
  for (int kc=0;kc<16;++kc){
    uint4 x = *reinterpret_cast<const uint4*>(xp + kc*8);
    a0=fdot2f(bc2(w[kc].x),bc2(x.x),a0);
    a1=fdot2f(bc2(w[kc].y),bc2(x.y),a1);
    a2=fdot2f(bc2(w[kc].z),bc2(x.z),a2);
    a3=fdot2f(bc2(w[kc].w),bc2(x.w),a3);
  }
  return (a0+a1)+(a2+a3);
}

// Pack f32 matrix (R x K slice at coloff, row stride ld) -> f16 [K/8][RT][8] at row_off.
__global__ void pack_k(const float* __restrict__ src, half_t* __restrict__ dst,
                       int R, int K, int ld, int coloff, int RT, int row_off){
  int idx = blockIdx.x*blockDim.x + threadIdx.x;
  if (idx >= R*K) return;
  int r = idx / K, k = idx - r*K;
  int kc = k >> 3, j = k & 7;
  dst[((size_t)kc*RT + row_off + r)*8 + j] = (half_t)src[(size_t)r*ld + coloff + k];
}

__launch_bounds__(512)
__attribute__((amdgpu_waves_per_eu(2,2)))
__global__ void gru_main(
    const float* __restrict__ received,
    const float* __restrict__ Wih0d0, const float* __restrict__ Wih0d1,
    const float* __restrict__ bx0d0, const float* __restrict__ bh0d0,
    const float* __restrict__ bx1d0, const float* __restrict__ bh1d0,
    const float* __restrict__ bx0d1, const float* __restrict__ bh0d1,
    const float* __restrict__ bx1d1, const float* __restrict__ bh1d1,
    const float* __restrict__ vW, const float* __restrict__ fc2b,
    const half_t* __restrict__ W0pack, const half_t* __restrict__ W1pack,
    const half_t* __restrict__ WsPack, const half_t* __restrict__ WhPack,
    const half_t* __restrict__ fc2Pack,
    half_t* __restrict__ o1h, half_t* __restrict__ o2h)
{
  const int dec = blockIdx.x >> 5;
  const int b   = blockIdx.x & 31;
  const int tid = threadIdx.x;

  const float* bx0  = dec ? bx0d1 : bx0d0;
  const float* bh0  = dec ? bh0d1 : bh0d0;
  const float* bx1  = dec ? bx1d1 : bx1d0;
  const float* bh1  = dec ? bh1d1 : bh1d0;
  const float* Wih0 = dec ? Wih0d1 : Wih0d0;
  const half_t* W0  = W0pack + (size_t)dec*49152;   // [16][384][8]  Whh0
  const half_t* W1  = W1pack + (size_t)dec*98304;   // [16][768][8]  rows 0-383 Wih1, 384-767 Whh1
  half_t* od = dec ? o2h : o1h;

  __shared__ __align__(16) half_t sh_hist[2][128][128];    // raw h history, col-swizzled by (t>>5)&1
  __shared__ __align__(16) half_t sh_histWh[2][128][128];  // hist @ Wh.T, row-swizzled by i&31
  __shared__ __align__(16) float  sh_hatt[2][128];
  __shared__ __align__(16) half_t sh_hatt_pk[2][128];
  __shared__ __align__(16) float  sh_hraw[2][128];
  __shared__ __align__(16) half_t sh_hraw_pk[2][128];
  __shared__ __align__(16) float  sh_gx[384];
  __shared__ __align__(16) float  sh_gh[384];
  __shared__ __align__(16) float  sh_g1x[384];
  __shared__ __align__(16) float  sh_g1h[384];
  __shared__ __align__(16) float  sh_sWs[2][128];
  __shared__ __align__(16) float  sh_logits[2][128];
  __shared__ __align__(16) float  sh_probs[2][128];
  __shared__ __align__(16) half_t sh_fc2in[2][256];        // [c | h_raw]
  __shared__ __align__(16) float  sh_x[2][4];              // double-buffered x
  __shared__ __align__(16) float  sh_vW[128];

  // ---- per-thread job setup (addresses / biases, loop-invariant) ----
  // JobA (P1, all): rows 0-383 = Whh0; tid 384-511 -> Whh1 rows 0-127 (packed rows 384-511)
  const half_t* ptrA; int strA; float bA;
  if (tid < 384){ ptrA = W0 + (size_t)tid*8; strA = 3072; bA = bh0[tid]; }
  else          { ptrA = W1 + (size_t)tid*8; strA = 6144; bA = bh1[tid-384]; }
  // JobB (P1, tid<256): Whh1 rows 128-383 (packed rows 512-767)
  const half_t* ptrB = W1 + (size_t)(512+tid)*8;    float bB = (tid<256)? bh1[128+tid] : 0.f;
  // JobC (P3, tid<384): Wih1 rows 0-383
  const half_t* ptrC = W1 + (size_t)tid*8;          float bC = (tid<384)? bx1[tid] : 0.f;
  // JobD (P5, all): mat = tid>>8 (0=Ws,1=Wh), l=(tid>>7)&1, row=tid&127
  const int dmat = tid>>8, dl = (tid>>7)&1, drow = tid&127;
  const half_t* ptrD = (dmat? WhPack : WsPack) + (size_t)drow*8;
  // JobE (P9, all): eh=k-half, el=layer, erow
  const int eh = tid&1, el = (tid>>8)&1, erow = (tid>>1)&127;
  const half_t* ptrE = fc2Pack + (size_t)eh*16384 + (size_t)erow*8;
  const float bE = eh ? 0.f : fc2b[erow];
  // gx0 weights (3 cols) held in regs
  float wx0=0.f,wx1=0.f,wx2=0.f,bgx=0.f;
  if (tid < 384){ wx0=Wih0[tid*3]; wx1=Wih0[tid*3+1]; wx2=Wih0[tid*3+2]; bgx=bx0[tid]; }

  const half_t* xA = (tid<384)? &sh_hatt_pk[0][0] : &sh_hatt_pk[1][0];
  const half_t* xB = &sh_hatt_pk[1][0];
  const half_t* xC = &sh_hraw_pk[0][0];
  const half_t* xD = &sh_hraw_pk[dl][0];
  const half_t* xE = &sh_fc2in[el][eh*128];

  uint4 bufP[16], bufQ[16];

  if (tid < 256){ int l=tid>>7, r=tid&127; sh_hatt[l][r]=0.f; sh_hatt_pk[l][r]=(half_t)0.f; }
  if (tid < 128) sh_vW[tid] = vW[tid];
  if (tid < 3)   sh_x[0][tid] = received[(b*128)*3 + tid];
  // prefetch step-0 JobA/JobB
  load16(ptrA, strA, bufP);
  if (tid < 256) load16(ptrB, 6144, bufQ);
  bar();

  for (int i=0; i<128; ++i){
    // ---- P1: gh0 (rows 0-383) + gh1 (rows 0-383 via A-tail and B) + gx0 ----
    {
      float g = dot16(bufP, xA, bA);
      if (tid < 384){
        sh_gh[tid] = g;
        float xv0=sh_x[i&1][0], xv1=sh_x[i&1][1], xv2=sh_x[i&1][2];
        sh_gx[tid] = bgx + wx0*xv0 + wx1*xv1 + wx2*xv2;
      } else {
        sh_g1h[tid-384] = g;
      }
      if (tid < 256){
        float g2 = dot16(bufQ, xB, bB);
        sh_g1h[128+tid] = g2;
      }
      if (tid < 384) load16(ptrC, 6144, bufQ);   // prefetch P3
    }
    bar();
    // ---- P2: layer0 cell ----
    if (tid < 128){
      float rr = sigmoidf_(sh_gx[tid]+sh_gh[tid]);
      float zz = sigmoidf_(sh_gx[128+tid]+sh_gh[128+tid]);
      float nn = tanhf_(sh_gx[256+tid] + rr*sh_gh[256+tid]);
      float h0 = (1.f-zz)*nn + zz*sh_hatt[0][tid];
      sh_hraw[0][tid]=h0;
      half_t hh=(half_t)h0;
      int pp = (((tid>>1) ^ (((i>>5)&1)<<4))<<1) | (tid&1);
      sh_hist[0][i][pp]=hh;
      sh_hraw_pk[0][tid]=hh; sh_fc2in[0][128+tid]=hh;
    }
    load16(ptrD, 1024, bufP);                    // prefetch P5
    bar();
    // ---- P3: g1x = Wih1 @ h0_raw ----
    if (tid < 384){
      sh_g1x[tid] = dot16(bufQ, xC, bC);
    }
    bar();
    // ---- P4: layer1 cell ----
    if (tid < 128){
      float rr = sigmoidf_(sh_g1x[tid]+sh_g1h[tid]);
      float zz = sigmoidf_(sh_g1x[128+tid]+sh_g1h[128+tid]);
      float nn = tanhf_(sh_g1x[256+tid] + rr*sh_g1h[256+tid]);
      float h1 = (1.f-zz)*nn + zz*sh_hatt[1][tid];
      sh_hraw[1][tid]=h1;
      half_t hh=(half_t)h1;
      int pp = (((tid>>1) ^ (((i>>5)&1)<<4))<<1) | (tid&1);
      sh_hist[1][i][pp]=hh;
      sh_hraw_pk[1][tid]=hh; sh_fc2in[1][128+tid]=hh;
      od[(size_t)(b*128+i)*128 + tid] = hh;
    }
    bar();
    // ---- P5: sWs / histWh projections ----
    {
      float dacc = dot16(bufP, xD, 0.f);
      if (dmat==0) sh_sWs[dl][drow] = dacc;
      else {
        int phys = (((drow>>1) ^ (i&31))<<1) | (drow&1);
        sh_histWh[dl][i][phys] = (half_t)dacc;
      }
      if (tid<3 && i<127) sh_x[(i+1)&1][tid] = received[(b*128+i+1)*3+tid];
      load16(ptrE, 1024, bufQ);                  // prefetch P9
    }
    bar();
    if (i > 0){
      // ---- P6: logits (2 lanes per (l,t)); prefetch next-step JobA ----
      load16(ptrA, strA, bufP);
      {
        int q=tid&1, t=(tid>>1)&127, l=tid>>8;
        float s=0.f;
        if (t<=i){
          const half_t* hrow = &sh_histWh[l][t][0];
          int tx = t&31;
          #pragma unroll 4
          for (int ji=0; ji<32; ++ji){
            int j = q*32+ji;
            half2_t h2 = *reinterpret_cast<const half2_t*>(hrow + ((j^tx)<<1));
            float2 sv = *reinterpret_cast<const float2*>(&sh_sWs[l][j*2]);
            float2 vv = *reinterpret_cast<const float2*>(&sh_vW[j*2]);
            s += tanhf_(sv.x + (float)h2[0])*vv.x;
            s += tanhf_(sv.y + (float)h2[1])*vv.y;
          }
        }
        s += __shfl_xor(s,1);
        if (q==0 && t<=i) sh_logits[l][t]=s;
      }
      bar();
      // ---- P7: masked softmax (no max-sub: |logit| <= sum|v| ~ 6) ----
      if (tid < 128){
        int l=tid>>6, lane=tid&63;
        float p0 = (lane<=i)    ? __expf(sh_logits[l][lane])    : 0.f;
        float p1 = (lane+64<=i) ? __expf(sh_logits[l][lane+64]) : 0.f;
        float ss = p0+p1;
        #pragma unroll
        for (int k=1;k<64;k<<=1) ss += __shfl_xor(ss,k);
        float inv = rcp_f(ss);
        sh_probs[l][lane]=p0*inv; sh_probs[l][lane+64]=p1*inv;
      }
      bar();
      // ---- P8: context ----
      {
        int q=tid&3, o2=(tid>>2)&63, l=tid>>8;
        int swz = (q&1)<<4;
        float c0=0.f,c1=0.f;
        int t0=q*32;
        int tend = (t0+32 < i+1) ? t0+32 : i+1;
        for (int t=t0; t<tend; ++t){
          float a = sh_probs[l][t];
          half2_t h2 = *reinterpret_cast<const half2_t*>(&sh_hist[l][t][(o2^swz)<<1]);
          c0 += a*(float)h2[0]; c1 += a*(float)h2[1];
        }
        c0 += __shfl_xor(c0,1); c1 += __shfl_xor(c1,1);
        c0 += __shfl_xor(c0,2); c1 += __shfl_xor(c1,2);
        if (q==0){
          sh_fc2in[l][o2*2]   = (half_t)c0;
          sh_fc2in[l][o2*2+1] = (half_t)c1;
        }
      }
      bar();
      // ---- P9: h_att = fc2 @ [c|h_raw] (k-split 2-way, shfl combine) ----
      {
        float e = dot16(bufQ, xE, bE);
        e += __shfl_xor(e, 1);
        if (!(tid&1)){ sh_hatt[el][erow]=e; sh_hatt_pk[el][erow]=(half_t)e; }
        if (tid < 256) load16(ptrB, 6144, bufQ); // prefetch next-step JobB
      }
    } else {
      load16(ptrA, strA, bufP);                  // prefetch next-step JobA
      if (tid < 256){
        int l=tid>>7, row=tid&127;
        float hv = sh_hraw[l][row];
        sh_hatt[l][row]=hv; sh_hatt_pk[l][row]=(half_t)hv;
      }
      if (tid < 256) load16(ptrB, 6144, bufQ);   // prefetch next-step JobB
    }
    bar();
  }
}

// Final: out[b,t] = sigmoid(tanh(out_W . [o1[b,t] | o2[b,min(t+10,127)]] + out_b))
__global__ void out_kernel(const half_t* __restrict__ o1h, const half_t* __restrict__ o2h,
                           const float* __restrict__ outW, const float* __restrict__ outb,
                           float* __restrict__ dout){
  int tid = blockIdx.x*blockDim.x + threadIdx.x;
  int q = tid&3, job = tid>>2;
  int b = job>>7, t = job&127;
  int t2 = t+10; if (t2>127) t2=127;
  const half_t* r1 = o1h + (size_t)(b*128+t)*128;
  const half_t* r2 = o2h + (size_t)(b*128+t2)*128;
  float acc=0.f;
  for (int j=q*32; j<q*32+32; ++j) acc += outW[j]*(float)r1[j];
  for (int j=q*32; j<q*32+32; ++j) acc += outW[128+j]*(float)r2[j];
  acc += __shfl_xor(acc,1);
  acc += __shfl_xor(acc,2);
  if (q==0){
    float d = tanhf_(acc + outb[0]);
    dout[job] = rcp_f(1.f+__expf(-d));
  }
}

static inline void launch_pack(const void* src, half_t* dst, int R, int K, int ld,
                               int coloff, int RT, int row_off, hipStream_t s){
  int total = R*K;
  pack_k<<<(total+255)/256, 256, 0, s>>>((const float*)src, dst, R, K, ld, coloff, RT, row_off);
}

extern "C" void kernel_launch(void* const* d_in, const int* in_sizes, int n_in,
                              void* d_out, int out_size, void* d_ws, size_t ws_size,
                              hipStream_t stream) {
  const float* received = (const float*)d_in[0];
  const float* Wih1_0 = (const float*)d_in[1];
  const float* Whh1_0 = (const float*)d_in[2];
  const float* bih1_0 = (const float*)d_in[3];
  const float* bhh1_0 = (const float*)d_in[4];
  const float* Wih1_1 = (const float*)d_in[5];
  const float* Whh1_1 = (const float*)d_in[6];
  const float* bih1_1 = (const float*)d_in[7];
  const float* bhh1_1 = (const float*)d_in[8];
  const float* Wih2_0 = (const float*)d_in[9];
  const float* Whh2_0 = (const float*)d_in[10];
  const float* bih2_0 = (const float*)d_in[11];
  const float* bhh2_0 = (const float*)d_in[12];
  const float* Wih2_1 = (const float*)d_in[13];
  const float* Whh2_1 = (const float*)d_in[14];
  const float* bih2_1 = (const float*)d_in[15];
  const float* bhh2_1 = (const float*)d_in[16];
  const float* attn_W = (const float*)d_in[17];
  const float* v_W    = (const float*)d_in[18];
  const float* fc2_W  = (const float*)d_in[19];
  const float* fc2_b  = (const float*)d_in[20];
  const float* out_W  = (const float*)d_in[21];
  const float* out_b  = (const float*)d_in[22];

  half_t* ws = (half_t*)d_ws;
  half_t* W0pack  = ws + 0;        // 2 x [16][384][8] = 98304
  half_t* W1pack  = ws + 98304;    // 2 x [16][768][8] = 196608
  half_t* WsPack  = ws + 294912;   // [16][128][8] = 16384
  half_t* WhPack  = ws + 311296;   // 16384
  half_t* fc2Pack = ws + 327552;   // [32][128][8] = 32768
  half_t* o1h     = ws + 360448;   // 32*128*128 = 524288
  half_t* o2h     = ws + 884736;   // 524288

  launch_pack(Whh1_0, W0pack,          384, 128, 128, 0, 384, 0, stream);
  launch_pack(Whh2_0, W0pack + 49152,  384, 128, 128, 0, 384, 0, stream);
  launch_pack(Wih1_1, W1pack,          384, 128, 128, 0, 768, 0, stream);
  launch_pack(Whh1_1, W1pack,          384, 128, 128, 0, 768, 384, stream);
  launch_pack(Wih2_1, W1pack + 98304,  384, 128, 128, 0, 768, 0, stream);
  launch_pack(Whh2_1, W1pack + 98304,  384, 128, 128, 0, 768, 384, stream);
  launch_pack(attn_W, WsPack,          128, 128, 256, 0,   128, 0, stream);
  launch_pack(attn_W, WhPack,          128, 128, 256, 128, 128, 0, stream);
  launch_pack(fc2_W,  fc2Pack,         128, 256, 256, 0,   128, 0, stream);

  gru_main<<<64, 512, 0, stream>>>(
      received,
      Wih1_0, Wih2_0,
      bih1_0, bhh1_0, bih1_1, bhh1_1,
      bih2_0, bhh2_0, bih2_1, bhh2_1,
      v_W, fc2_b,
      W0pack, W1pack, WsPack, WhPack, fc2Pack,
      o1h, o2h);

  out_kernel<<<64, 256, 0, stream>>>(o1h, o2h, out_W, out_b, (float*)d_out);
}

// Round 5
// 1624.517 us; speedup vs baseline: 1.3328x; 1.3251x over previous
//
#include <hip/hip_runtime.h>

typedef _Float16 half_t;
typedef __attribute__((ext_vector_type(2))) _Float16 half2_t;

union U4u { uint4 v; unsigned int u[4]; };

__device__ __forceinline__ half2_t bc2(unsigned int u){ return __builtin_bit_cast(half2_t, u); }
__device__ __forceinline__ float fdot2f(half2_t a, half2_t b, float c){
  return __builtin_amdgcn_fdot2(a, b, c, false);
}
__device__ __forceinline__ float rcp_f(float x){ return __builtin_amdgcn_rcpf(x); }
__device__ __forceinline__ float sigmoidf_(float x){ return rcp_f(1.0f+__expf(-x)); }
__device__ __forceinline__ float tanhf_(float x){ return 1.0f - 2.0f*rcp_f(__expf(2.0f*x)+1.0f); }

// Barrier WITHOUT vmcnt drain: LDS ordering only; global prefetches stay in flight.
__device__ __forceinline__ void bar(){
  asm volatile("s_waitcnt lgkmcnt(0)\n\ts_barrier" ::: "memory");
}

// k=32 quarter dot: 4 resident weight uint4 vs 4 x uint4 (16 fdot2, 4 chains)
__device__ __forceinline__ float dotq(const uint4 (&w)[4], const uint4 (&x)[4]){
  float a0=0.f,a1=0.f,a2=0.f,a3=0.f;
  #pragma unroll
  for (int m=0;m<4;++m){
    a0=fdot2f(bc2(w[m].x),bc2(x[m].x),a0);
    a1=fdot2f(bc2(w[m].y),bc2(x[m].y),a1);
    a2=fdot2f(bc2(w[m].z),bc2(x[m].z),a2);
    a3=fdot2f(bc2(w[m].w),bc2(x[m].w),a3);
  }
  return (a0+a1)+(a2+a3);
}

// Pack f32 matrix (R x K slice at coloff, row stride ld) -> f16 [K/8][RT][8] at row_off.
__global__ void pack_k(const float* __restrict__ src, half_t* __restrict__ dst,
                       int R, int K, int ld, int coloff, int RT, int row_off){
  int idx = blockIdx.x*blockDim.x + threadIdx.x;
  if (idx >= R*K) return;
  int r = idx / K, k = idx - r*K;
  int kc = k >> 3, j = k & 7;
  dst[((size_t)kc*RT + row_off + r)*8 + j] = (half_t)src[(size_t)r*ld + coloff + k];
}

__global__ __attribute__((amdgpu_flat_work_group_size(512,512), amdgpu_waves_per_eu(1,2)))
void gru_main(
    const float* __restrict__ received,
    const float* __restrict__ Wih0d0, const float* __restrict__ Wih0d1,
    const float* __restrict__ bx0d0, const float* __restrict__ bh0d0,
    const float* __restrict__ bx1d0, const float* __restrict__ bh1d0,
    const float* __restrict__ bx0d1, const float* __restrict__ bh0d1,
    const float* __restrict__ bx1d1, const float* __restrict__ bh1d1,
    const float* __restrict__ vW, const float* __restrict__ fc2b,
    const half_t* __restrict__ W0pack, const half_t* __restrict__ W1pack,
    const half_t* __restrict__ WsPack, const half_t* __restrict__ WhPack,
    const half_t* __restrict__ fc2Pack,
    half_t* __restrict__ o1h, half_t* __restrict__ o2h)
{
  const int dec = blockIdx.x >> 5;
  const int b   = blockIdx.x & 31;
  const int tid = threadIdx.x;
  const int g   = tid>>2;      // 128 groups of 4 lanes
  const int q   = tid&3;       // k-quarter lane

  const float* bx0  = dec ? bx0d1 : bx0d0;
  const float* bh0  = dec ? bh0d1 : bh0d0;
  const float* bx1  = dec ? bx1d1 : bx1d0;
  const float* bh1  = dec ? bh1d1 : bh1d0;
  const float* Wih0 = dec ? Wih0d1 : Wih0d0;
  const half_t* W0  = W0pack + (size_t)dec*49152;   // [16][384][8]  Whh0
  const half_t* W1  = W1pack + (size_t)dec*98304;   // [16][768][8]  rows 0-383 Wih1, 384-767 Whh1
  half_t* od = dec ? o2h : o1h;

  __shared__ __align__(16) half_t sh_hist[2][128][128];   // raw h history (col-swizzled)
  __shared__ __align__(16) half_t sh_WsWh[2][16][128][8]; // Ws/Wh pinned in LDS
  __shared__ __align__(16) half_t sh_staging[2][128];     // histWh row-i staging
  __shared__ __align__(16) float  sh_gx[384];
  __shared__ __align__(16) float  sh_gh[384];
  __shared__ __align__(16) float  sh_g1x[384];
  __shared__ __align__(16) float  sh_g1h[384];
  __shared__ __align__(16) float  sh_sWs[2][128];
  __shared__ __align__(16) float  sh_logits[2][128];
  __shared__ __align__(16) float  sh_probs[2][128];
  __shared__ __align__(16) float  sh_hatt[2][128];
  __shared__ __align__(16) half_t sh_hatt_pk[2][128];
  __shared__ __align__(16) float  sh_hraw[2][128];
  __shared__ __align__(16) half_t sh_hraw_pk[2][128];
  __shared__ __align__(16) half_t sh_fc2in[2][256];
  __shared__ __align__(16) float  sh_x[2][4];
  __shared__ __align__(16) float  sh_vW[128];

  // ---------- resident weights (loop-invariant VGPRs) ----------
  // P1: 6 rows (k-quarter q) of Whh0 (groups 0-63) or Whh1 (groups 64-127)
  const half_t* baseA; int RTA, rowA0;
  if (g<64){ baseA=W0; RTA=384; rowA0=6*g; }
  else     { baseA=W1; RTA=768; rowA0=384+6*(g-64); }
  uint4 wA[6][4];
  #pragma unroll
  for (int n=0;n<6;++n)
    #pragma unroll
    for (int m=0;m<4;++m)
      wA[n][m] = *reinterpret_cast<const uint4*>(baseA + ((size_t)(4*q+m)*RTA + rowA0+n)*8);
  const float biasA0 = (g<64)? bh0[rowA0+q] : bh1[rowA0-384+q];
  const float biasA1 = (q<2)? ((g<64)? bh0[rowA0+q+4] : bh1[rowA0-384+q+4]) : 0.f;

  // P3: 3 rows of Wih1
  const int rowC0 = 3*g;
  uint4 wC[3][4];
  #pragma unroll
  for (int n=0;n<3;++n)
    #pragma unroll
    for (int m=0;m<4;++m)
      wC[n][m] = *reinterpret_cast<const uint4*>(W1 + ((size_t)(4*q+m)*768 + rowC0+n)*8);
  const float biasC = (q<3)? bx1[rowC0+q] : 0.f;

  // gx0 weights (3 cols)
  float wx0=0.f,wx1=0.f,wx2=0.f,bgx=0.f;
  if (tid < 384){ wx0=Wih0[tid*3]; wx1=Wih0[tid*3+1]; wx2=Wih0[tid*3+2]; bgx=bx0[tid]; }

  // P9: fc2 bias (group row)
  const float bE = fc2b[g];

  // P6 owner-resident histWh half-row
  const int l6 = tid>>8, t6 = (tid>>1)&127, q6 = tid&1;
  uint4 myhw[8];
  #pragma unroll
  for (int c=0;c<8;++c) myhw[c] = make_uint4(0u,0u,0u,0u);

  // ---------- LDS init: Ws -> sh_WsWh[0] (2048 uint4), Wh -> sh_WsWh[1] (+2048) ----------
  {
    uint4* shp = reinterpret_cast<uint4*>(&sh_WsWh[0][0][0][0]);
    const uint4* g0 = reinterpret_cast<const uint4*>(WsPack);
    const uint4* g1 = reinterpret_cast<const uint4*>(WhPack);
    #pragma unroll
    for (int k=0;k<4;++k){
      shp[tid + k*512]        = g0[tid + k*512];
      shp[2048 + tid + k*512] = g1[tid + k*512];
    }
  }
  if (tid < 256){ int l=tid>>7, r=tid&127; sh_hatt[l][r]=0.f; sh_hatt_pk[l][r]=(half_t)0.f; }
  if (tid < 128) sh_vW[tid] = vW[tid];
  if (tid < 3)   sh_x[0][tid] = received[(b*128)*3 + tid];
  bar();

  for (int i=0; i<128; ++i){
    // ---- P1: gh0 = Whh0@hatt0 (g<64) / g1h = Whh1@hatt1 (g>=64); gx0 ----
    {
      const half_t* xp = &sh_hatt_pk[(g<64)?0:1][q*32];
      uint4 xr[4];
      #pragma unroll
      for (int m=0;m<4;++m) xr[m] = *reinterpret_cast<const uint4*>(xp + m*8);
      float a0_=dotq(wA[0],xr), a1_=dotq(wA[1],xr), a2_=dotq(wA[2],xr);
      float a3_=dotq(wA[3],xr), a4_=dotq(wA[4],xr), a5_=dotq(wA[5],xr);
      a0_ += __shfl_xor(a0_,1); a0_ += __shfl_xor(a0_,2);
      a1_ += __shfl_xor(a1_,1); a1_ += __shfl_xor(a1_,2);
      a2_ += __shfl_xor(a2_,1); a2_ += __shfl_xor(a2_,2);
      a3_ += __shfl_xor(a3_,1); a3_ += __shfl_xor(a3_,2);
      a4_ += __shfl_xor(a4_,1); a4_ += __shfl_xor(a4_,2);
      a5_ += __shfl_xor(a5_,1); a5_ += __shfl_xor(a5_,2);
      float* dst = (g<64)? sh_gh : sh_g1h;
      int rbase  = (g<64)? rowA0 : rowA0-384;
      float lo = (q==0)? a0_ : (q==1)? a1_ : (q==2)? a2_ : a3_;
      dst[rbase+q] = lo + biasA0;
      if (q<2) dst[rbase+q+4] = ((q==0)? a4_ : a5_) + biasA1;
      if (tid < 384){
        float xv0=sh_x[i&1][0], xv1=sh_x[i&1][1], xv2=sh_x[i&1][2];
        sh_gx[tid] = bgx + wx0*xv0 + wx1*xv1 + wx2*xv2;
      }
    }
    bar();
    // ---- P2: layer0 cell ----
    if (tid < 128){
      float rr = sigmoidf_(sh_gx[tid]+sh_gh[tid]);
      float zz = sigmoidf_(sh_gx[128+tid]+sh_gh[128+tid]);
      float nn = tanhf_(sh_gx[256+tid] + rr*sh_gh[256+tid]);
      float h0 = (1.f-zz)*nn + zz*sh_hatt[0][tid];
      sh_hraw[0][tid]=h0;
      half_t hh=(half_t)h0;
      int pp = (((tid>>1) ^ (((i>>5)&1)<<4))<<1) | (tid&1);
      sh_hist[0][i][pp]=hh;
      sh_hraw_pk[0][tid]=hh; sh_fc2in[0][128+tid]=hh;
    }
    bar();
    // ---- P3: g1x = Wih1 @ h0_raw ----
    {
      const half_t* xp = &sh_hraw_pk[0][q*32];
      uint4 xr[4];
      #pragma unroll
      for (int m=0;m<4;++m) xr[m] = *reinterpret_cast<const uint4*>(xp + m*8);
      float a0_=dotq(wC[0],xr), a1_=dotq(wC[1],xr), a2_=dotq(wC[2],xr);
      a0_ += __shfl_xor(a0_,1); a0_ += __shfl_xor(a0_,2);
      a1_ += __shfl_xor(a1_,1); a1_ += __shfl_xor(a1_,2);
      a2_ += __shfl_xor(a2_,1); a2_ += __shfl_xor(a2_,2);
      if (q<3){
        float lo = (q==0)? a0_ : (q==1)? a1_ : a2_;
        sh_g1x[rowC0+q] = lo + biasC;
      }
    }
    bar();
    // ---- P4: layer1 cell + raw output ----
    if (tid < 128){
      float rr = sigmoidf_(sh_g1x[tid]+sh_g1h[tid]);
      float zz = sigmoidf_(sh_g1x[128+tid]+sh_g1h[128+tid]);
      float nn = tanhf_(sh_g1x[256+tid] + rr*sh_g1h[256+tid]);
      float h1 = (1.f-zz)*nn + zz*sh_hatt[1][tid];
      sh_hraw[1][tid]=h1;
      half_t hh=(half_t)h1;
      int pp = (((tid>>1) ^ (((i>>5)&1)<<4))<<1) | (tid&1);
      sh_hist[1][i][pp]=hh;
      sh_hraw_pk[1][tid]=hh; sh_fc2in[1][128+tid]=hh;
      od[(size_t)(b*128+i)*128 + tid] = hh;
    }
    bar();
    // ---- P5: sWs[l] = Ws@h_raw[l]; staging[l] = Wh@h_raw[l] (from LDS-pinned Ws/Wh) ----
    {
      const int mat5 = tid>>8, l5=(tid>>7)&1, row5=tid&127;
      const half_t* wbase = &sh_WsWh[mat5][0][row5][0];
      const half_t* xbase = &sh_hraw_pk[l5][0];
      float a0=0.f,a1=0.f,a2=0.f,a3=0.f;
      #pragma unroll
      for (int kc=0;kc<16;++kc){
        uint4 w = *reinterpret_cast<const uint4*>(wbase + kc*1024);
        uint4 x = *reinterpret_cast<const uint4*>(xbase + kc*8);
        a0=fdot2f(bc2(w.x),bc2(x.x),a0);
        a1=fdot2f(bc2(w.y),bc2(x.y),a1);
        a2=fdot2f(bc2(w.z),bc2(x.z),a2);
        a3=fdot2f(bc2(w.w),bc2(x.w),a3);
      }
      float acc=(a0+a1)+(a2+a3);
      if (mat5==0) sh_sWs[l5][row5]=acc;
      else         sh_staging[l5][row5]=(half_t)acc;
      if (tid<3 && i<127) sh_x[(i+1)&1][tid] = received[(b*128+i+1)*3+tid];
    }
    bar();
    // ---- pickup: histWh row i -> owner registers ----
    if (t6 == i){
      const uint4* sp = reinterpret_cast<const uint4*>(&sh_staging[l6][q6*64]);
      #pragma unroll
      for (int c=0;c<8;++c) myhw[c]=sp[c];
    }
    if (i > 0){
      // ---- P6: logits (pure-reg histWh + LDS broadcast sWs/vW) ----
      {
        float s=0.f;
        if (t6<=i){
          const float* sw = &sh_sWs[l6][q6*64];
          const float* vv = &sh_vW[q6*64];
          #pragma unroll
          for (int j=0;j<32;++j){
            U4u uu; uu.v = myhw[j>>2];
            half2_t h2 = bc2(uu.u[j&3]);
            float2 sv = *reinterpret_cast<const float2*>(sw+2*j);
            float2 vf = *reinterpret_cast<const float2*>(vv+2*j);
            s += tanhf_(sv.x+(float)h2[0])*vf.x;
            s += tanhf_(sv.y+(float)h2[1])*vf.y;
          }
        }
        s += __shfl_xor(s,1);
        if (q6==0 && t6<=i) sh_logits[l6][t6]=s;
      }
      bar();
      // ---- P7: masked softmax (|logit| <= sum|v| ~ 6, no max-sub) ----
      if (tid < 128){
        int l=tid>>6, lane=tid&63;
        float p0 = (lane<=i)    ? __expf(sh_logits[l][lane])    : 0.f;
        float p1 = (lane+64<=i) ? __expf(sh_logits[l][lane+64]) : 0.f;
        float ss = p0+p1;
        #pragma unroll
        for (int k=1;k<64;k<<=1) ss += __shfl_xor(ss,k);
        float inv = rcp_f(ss);
        sh_probs[l][lane]=p0*inv; sh_probs[l][lane+64]=p1*inv;
      }
      bar();
      // ---- P8: context + fc2 prefetch into registers ----
      uint4 wE[8];
      {
        #pragma unroll
        for (int c=0;c<8;++c)
          wE[c] = *reinterpret_cast<const uint4*>(fc2Pack + ((size_t)(q*8+c)*128 + g)*8);
        int o2=(tid>>2)&63, l8=tid>>8;
        int swz=(q&1)<<4;
        float c0=0.f,c1=0.f;
        int t0=q*32;
        int tend = (t0+32 < i+1) ? t0+32 : i+1;
        for (int t=t0; t<tend; ++t){
          float a = sh_probs[l8][t];
          half2_t h2 = *reinterpret_cast<const half2_t*>(&sh_hist[l8][t][(o2^swz)<<1]);
          c0 += a*(float)h2[0]; c1 += a*(float)h2[1];
        }
        c0 += __shfl_xor(c0,1); c1 += __shfl_xor(c1,1);
        c0 += __shfl_xor(c0,2); c1 += __shfl_xor(c1,2);
        if (q==0){
          sh_fc2in[l8][o2*2]   = (half_t)c0;
          sh_fc2in[l8][o2*2+1] = (half_t)c1;
        }
      }
      bar();
      // ---- P9: h_att[l] = fc2 @ [c|h_raw] (wE shared across both layers) ----
      {
        const half_t* x0 = &sh_fc2in[0][q*64];
        const half_t* x1 = &sh_fc2in[1][q*64];
        float e0,e1;
        { float a0=0.f,a1=0.f,a2=0.f,a3=0.f;
          #pragma unroll
          for (int c=0;c<8;++c){
            uint4 x = *reinterpret_cast<const uint4*>(x0 + c*8);
            a0=fdot2f(bc2(wE[c].x),bc2(x.x),a0);
            a1=fdot2f(bc2(wE[c].y),bc2(x.y),a1);
            a2=fdot2f(bc2(wE[c].z),bc2(x.z),a2);
            a3=fdot2f(bc2(wE[c].w),bc2(x.w),a3);
          }
          e0=(a0+a1)+(a2+a3); }
        { float a0=0.f,a1=0.f,a2=0.f,a3=0.f;
          #pragma unroll
          for (int c=0;c<8;++c){
            uint4 x = *reinterpret_cast<const uint4*>(x1 + c*8);
            a0=fdot2f(bc2(wE[c].x),bc2(x.x),a0);
            a1=fdot2f(bc2(wE[c].y),bc2(x.y),a1);
            a2=fdot2f(bc2(wE[c].z),bc2(x.z),a2);
            a3=fdot2f(bc2(wE[c].w),bc2(x.w),a3);
          }
          e1=(a0+a1)+(a2+a3); }
        e0 += __shfl_xor(e0,1); e0 += __shfl_xor(e0,2);
        e1 += __shfl_xor(e1,1); e1 += __shfl_xor(e1,2);
        if (q==0){ float v=e0+bE; sh_hatt[0][g]=v; sh_hatt_pk[0][g]=(half_t)v; }
        else if (q==1){ float v=e1+bE; sh_hatt[1][g]=v; sh_hatt_pk[1][g]=(half_t)v; }
      }
    } else {
      if (tid < 256){
        int l=tid>>7, row=tid&127;
        float hv = sh_hraw[l][row];
        sh_hatt[l][row]=hv; sh_hatt_pk[l][row]=(half_t)hv;
      }
    }
    bar();
  }
}

// Final: out[b,t] = sigmoid(tanh(out_W . [o1[b,t] | o2[b,min(t+10,127)]] + out_b))
__global__ void out_kernel(const half_t* __restrict__ o1h, const half_t* __restrict__ o2h,
                           const float* __restrict__ outW, const float* __restrict__ outb,
                           float* __restrict__ dout){
  int tid = blockIdx.x*blockDim.x + threadIdx.x;
  int q = tid&3, job = tid>>2;
  int b = job>>7, t = job&127;
  int t2 = t+10; if (t2>127) t2=127;
  const half_t* r1 = o1h + (size_t)(b*128+t)*128;
  const half_t* r2 = o2h + (size_t)(b*128+t2)*128;
  float acc=0.f;
  for (int j=q*32; j<q*32+32; ++j) acc += outW[j]*(float)r1[j];
  for (int j=q*32; j<q*32+32; ++j) acc += outW[128+j]*(float)r2[j];
  acc += __shfl_xor(acc,1);
  acc += __shfl_xor(acc,2);
  if (q==0){
    float d = tanhf_(acc + outb[0]);
    dout[job] = rcp_f(1.f+__expf(-d));
  }
}

static inline void launch_pack(const void* src, half_t* dst, int R, int K, int ld,
                               int coloff, int RT, int row_off, hipStream_t s){
  int total = R*K;
  pack_k<<<(total+255)/256, 256, 0, s>>>((const float*)src, dst, R, K, ld, coloff, RT, row_off);
}

extern "C" void kernel_launch(void* const* d_in, const int* in_sizes, int n_in,
                              void* d_out, int out_size, void* d_ws, size_t ws_size,
                              hipStream_t stream) {
  const float* received = (const float*)d_in[0];
  const float* Wih1_0 = (const float*)d_in[1];
  const float* Whh1_0 = (const float*)d_in[2];
  const float* bih1_0 = (const float*)d_in[3];
  const float* bhh1_0 = (const float*)d_in[4];
  const float* Wih1_1 = (const float*)d_in[5];
  const float* Whh1_1 = (const float*)d_in[6];
  const float* bih1_1 = (const float*)d_in[7];
  const float* bhh1_1 = (const float*)d_in[8];
  const float* Wih2_0 = (const float*)d_in[9];
  const float* Whh2_0 = (const float*)d_in[10];
  const float* bih2_0 = (const float*)d_in[11];
  const float* bhh2_0 = (const float*)d_in[12];
  const float* Wih2_1 = (const float*)d_in[13];
  const float* Whh2_1 = (const float*)d_in[14];
  const float* bih2_1 = (const float*)d_in[15];
  const float* bhh2_1 = (const float*)d_in[16];
  const float* attn_W = (const float*)d_in[17];
  const float* v_W    = (const float*)d_in[18];
  const float* fc2_W  = (const float*)d_in[19];
  const float* fc2_b  = (const float*)d_in[20];
  const float* out_W  = (const float*)d_in[21];
  const float* out_b  = (const float*)d_in[22];

  half_t* ws = (half_t*)d_ws;
  half_t* W0pack  = ws + 0;        // 2 x [16][384][8] = 98304
  half_t* W1pack  = ws + 98304;    // 2 x [16][768][8] = 196608
  half_t* WsPack  = ws + 294912;   // [16][128][8] = 16384
  half_t* WhPack  = ws + 311296;   // 16384
  half_t* fc2Pack = ws + 327552;   // [32][128][8] = 32768
  half_t* o1h     = ws + 360448;   // 32*128*128 = 524288
  half_t* o2h     = ws + 884736;   // 524288

  launch_pack(Whh1_0, W0pack,          384, 128, 128, 0, 384, 0, stream);
  launch_pack(Whh2_0, W0pack + 49152,  384, 128, 128, 0, 384, 0, stream);
  launch_pack(Wih1_1, W1pack,          384, 128, 128, 0, 768, 0, stream);
  launch_pack(Whh1_1, W1pack,          384, 128, 128, 0, 768, 384, stream);
  launch_pack(Wih2_1, W1pack + 98304,  384, 128, 128, 0, 768, 0, stream);
  launch_pack(Whh2_1, W1pack + 98304,  384, 128, 128, 0, 768, 384, stream);
  launch_pack(attn_W, WsPack,          128, 128, 256, 0,   128, 0, stream);
  launch_pack(attn_W, WhPack,          128, 128, 256, 128, 128, 0, stream);
  launch_pack(fc2_W,  fc2Pack,         128, 256, 256, 0,   128, 0, stream);

  gru_main<<<64, 512, 0, stream>>>(
      received,
      Wih1_0, Wih2_0,
      bih1_0, bhh1_0, bih1_1, bhh1_1,
      bih2_0, bhh2_0, bih2_1, bhh2_1,
      v_W, fc2_b,
      W0pack, W1pack, WsPack, WhPack, fc2Pack,
      o1h, o2h);

  out_kernel<<<64, 256, 0, stream>>>(o1h, o2h, out_W, out_b, (float*)d_out);
}